// Round 1
// baseline (6351.155 us; speedup 1.0000x reference)
//
#include <hip/hip_runtime.h>

#define N_NODES 100000
#define E_EDGES 3200000
#define IN_F 128
#define HID 32
#define PROP 8

// ---------- degree / coef precompute ----------
__global__ void count_deg_kernel(const int* __restrict__ idx, int* __restrict__ deg, int n) {
    int i = blockIdx.x * blockDim.x + threadIdx.x;
    if (i < n) atomicAdd(&deg[idx[i]], 1);
}

__global__ void inv_sqrt_kernel(const int* __restrict__ deg, float* __restrict__ inv, int n) {
    int i = blockIdx.x * blockDim.x + threadIdx.x;
    if (i < n) inv[i] = rsqrtf(fmaxf((float)deg[i], 1.0f));
}

__global__ void coef_kernel(const int* __restrict__ src, const int* __restrict__ dst,
                            const float* __restrict__ inv_out, const float* __restrict__ inv_in,
                            float sign, float* __restrict__ coef, int n) {
    int e = blockIdx.x * blockDim.x + threadIdx.x;
    if (e < n) coef[e] = sign * inv_out[src[e]] * inv_in[dst[e]];
}

// ---------- MLP ----------
// x = in_feat @ W1 + b1, plus per-column sum/sumsq for batchnorm stats.
__global__ __launch_bounds__(256) void mlp1_kernel(const float* __restrict__ in_feat,
        const float* __restrict__ W1, const float* __restrict__ b1,
        float* __restrict__ x, float* __restrict__ gsum, float* __restrict__ gsumsq) {
    __shared__ float sW1[IN_F * HID];   // 16 KB
    __shared__ float sRow[8][IN_F];     // 4 KB
    __shared__ float sSum[HID], sSumSq[HID];
    int tid = threadIdx.x;
    for (int i = tid; i < IN_F * HID; i += 256) sW1[i] = W1[i];
    int nb = blockIdx.x * 8;
    for (int i = tid; i < 8 * IN_F; i += 256) {
        int r = i >> 7, c = i & 127;
        sRow[r][c] = in_feat[(size_t)(nb + r) * IN_F + c];
    }
    if (tid < HID) { sSum[tid] = 0.f; sSumSq[tid] = 0.f; }
    __syncthreads();
    int k = tid & 31, r = tid >> 5;
    float acc = b1[k];
    #pragma unroll 8
    for (int j = 0; j < IN_F; ++j) acc = fmaf(sRow[r][j], sW1[j * HID + k], acc);
    x[(size_t)(nb + r) * HID + k] = acc;
    atomicAdd(&sSum[k], acc);
    atomicAdd(&sSumSq[k], acc * acc);
    __syncthreads();
    if (tid < HID) {
        atomicAdd(&gsum[tid], sSum[tid]);
        atomicAdd(&gsumsq[tid], sSumSq[tid]);
    }
}

__global__ void bnparam_kernel(const float* __restrict__ gsum, const float* __restrict__ gsumsq,
        const float* __restrict__ gamma, const float* __restrict__ beta, float* __restrict__ params) {
    int k = threadIdx.x;
    if (k < HID) {
        float mu  = gsum[k]  * (1.0f / (float)N_NODES);
        float var = gsumsq[k] * (1.0f / (float)N_NODES) - mu * mu;
        float s = gamma[k] * rsqrtf(var + 1e-5f);
        params[k]       = s;
        params[HID + k] = beta[k] - mu * s;
    }
}

// ori_h = relu(bn(x)) @ W2 + b2
__global__ __launch_bounds__(256) void mlp2_kernel(const float* __restrict__ x,
        const float* __restrict__ params, const float* __restrict__ W2,
        const float* __restrict__ b2, float* __restrict__ ori_h) {
    __shared__ float sW2[HID * HID];
    __shared__ float sXn[8][HID];
    int tid = threadIdx.x;
    for (int i = tid; i < HID * HID; i += 256) sW2[i] = W2[i];
    int nb = blockIdx.x * 8;
    int k = tid & 31, r = tid >> 5;
    float v = x[(size_t)(nb + r) * HID + k];
    v = fmaxf(fmaf(v, params[k], params[HID + k]), 0.f);
    sXn[r][k] = v;
    __syncthreads();
    float acc = b2[k];
    #pragma unroll
    for (int j = 0; j < HID; ++j) acc = fmaf(sXn[r][j], sW2[j * HID + k], acc);
    ori_h[(size_t)(nb + r) * HID + k] = acc;
}

// ---------- propagation ----------
__global__ void copy_kernel(const float4* __restrict__ s, float4* __restrict__ d, int n4) {
    int i = blockIdx.x * blockDim.x + threadIdx.x;
    if (i < n4) d[i] = s[i];
}

// one thread per (edge, feature); wave64 = 2 edges x 32 contiguous floats
__global__ __launch_bounds__(256) void scatter_kernel(const int* __restrict__ src,
        const int* __restrict__ dst, const float* __restrict__ coef,
        const float* __restrict__ h, float* __restrict__ hn) {
    int idx = blockIdx.x * 256 + threadIdx.x;   // grid sized exactly E*32
    int e = idx >> 5, f = idx & 31;
    int u = src[e], v = dst[e];
    float c = coef[e];
    atomicAdd(&hn[(size_t)v * HID + f], c * h[(size_t)u * HID + f]);
}

extern "C" void kernel_launch(void* const* d_in, const int* in_sizes, int n_in,
                              void* d_out, int out_size, void* d_ws, size_t ws_size,
                              hipStream_t stream) {
    const float* in_feat = (const float*)d_in[0];
    const float* W1    = (const float*)d_in[1];
    const float* b1    = (const float*)d_in[2];
    const float* gamma = (const float*)d_in[3];
    const float* beta  = (const float*)d_in[4];
    const float* W2    = (const float*)d_in[5];
    const float* b2    = (const float*)d_in[6];
    const int* src  = (const int*)d_in[7];
    const int* dst  = (const int*)d_in[8];
    const int* nsrc = (const int*)d_in[9];
    const int* ndst = (const int*)d_in[10];
    float* out = (float*)d_out;

    // workspace layout (floats)
    float* ws     = (float*)d_ws;
    float* x      = ws;                                   // N*32 (reused as ping-pong buf after MLP)
    float* ori_h  = x + (size_t)N_NODES * HID;            // N*32
    float* hA     = ori_h + (size_t)N_NODES * HID;        // N*32
    float* coef_p = hA + (size_t)N_NODES * HID;           // E
    float* coef_n = coef_p + E_EDGES;                     // E
    float* invs   = coef_n + E_EDGES;                     // 4*N  [out_p, in_p, out_n, in_n]
    float* gsum   = invs + 4 * (size_t)N_NODES;           // 32
    float* gsumsq = gsum + HID;                           // 32
    float* params = gsumsq + HID;                         // 64
    int*   degs   = (int*)(params + 2 * HID);             // 4*N ints

    hipMemsetAsync(degs, 0, 4 * (size_t)N_NODES * sizeof(int), stream);
    hipMemsetAsync(gsum, 0, 2 * HID * sizeof(float), stream);

    const int EB = E_EDGES / 256;          // 12500, exact
    count_deg_kernel<<<EB, 256, 0, stream>>>(src,  degs + 0 * N_NODES, E_EDGES);
    count_deg_kernel<<<EB, 256, 0, stream>>>(dst,  degs + 1 * N_NODES, E_EDGES);
    count_deg_kernel<<<EB, 256, 0, stream>>>(nsrc, degs + 2 * N_NODES, E_EDGES);
    count_deg_kernel<<<EB, 256, 0, stream>>>(ndst, degs + 3 * N_NODES, E_EDGES);
    inv_sqrt_kernel<<<(4 * N_NODES + 255) / 256, 256, 0, stream>>>(degs, invs, 4 * N_NODES);
    coef_kernel<<<EB, 256, 0, stream>>>(src,  dst,  invs,               invs + N_NODES,     1.f, coef_p, E_EDGES);
    coef_kernel<<<EB, 256, 0, stream>>>(nsrc, ndst, invs + 2 * N_NODES, invs + 3 * N_NODES, -1.f, coef_n, E_EDGES);

    mlp1_kernel<<<N_NODES / 8, 256, 0, stream>>>(in_feat, W1, b1, x, gsum, gsumsq);
    bnparam_kernel<<<1, 64, 0, stream>>>(gsum, gsumsq, gamma, beta, params);
    mlp2_kernel<<<N_NODES / 8, 256, 0, stream>>>(x, params, W2, b2, ori_h);

    // propagation: h_next = ori_h + sum_pos coef*h[src] + sum_neg (-coef)*h[src]
    const int n4 = N_NODES * HID / 4;
    const int SB = E_EDGES * 32 / 256;     // 400000, exact
    const float* h = ori_h;
    float* bufs[2] = { hA, x };            // x is free after mlp2
    for (int it = 0; it < PROP; ++it) {
        float* hn = (it == PROP - 1) ? out : bufs[it & 1];
        copy_kernel<<<(n4 + 255) / 256, 256, 0, stream>>>((const float4*)ori_h, (float4*)hn, n4);
        scatter_kernel<<<SB, 256, 0, stream>>>(src,  dst,  coef_p, h, hn);
        scatter_kernel<<<SB, 256, 0, stream>>>(nsrc, ndst, coef_n, h, hn);
        h = hn;
    }
}

// Round 2
// 2478.825 us; speedup vs baseline: 2.5622x; 2.5622x over previous
//
#include <hip/hip_runtime.h>

#define N_NODES 100000
#define E_EDGES 3200000
#define IN_F 128
#define HID 32
#define PROP 8

// ---------- degree histograms (all 4 in one kernel) ----------
__global__ __launch_bounds__(256) void deg4_kernel(const int* __restrict__ s, const int* __restrict__ d,
        const int* __restrict__ ns, const int* __restrict__ nd, int* __restrict__ degs) {
    int e = blockIdx.x * 256 + threadIdx.x;
    if (e < E_EDGES) {
        atomicAdd(&degs[s[e]], 1);
        atomicAdd(&degs[N_NODES + d[e]], 1);
        atomicAdd(&degs[2 * N_NODES + ns[e]], 1);
        atomicAdd(&degs[3 * N_NODES + nd[e]], 1);
    }
}

__global__ void inv_sqrt_kernel(const int* __restrict__ deg, float* __restrict__ inv, int n) {
    int i = blockIdx.x * blockDim.x + threadIdx.x;
    if (i < n) inv[i] = rsqrtf(fmaxf((float)deg[i], 1.0f));
}

// ---------- CSR build: scan of combined in-degree, then placement ----------
#define SCAN_T 1024
__global__ __launch_bounds__(SCAN_T) void scan_kernel(const int* __restrict__ degs,
        int* __restrict__ row_ptr, int* __restrict__ cursor) {
    __shared__ int s[SCAN_T];
    int t = threadIdx.x;
    const int chunk = 98;                       // 1024*98 = 100352 >= N
    int lo = t * chunk;
    int sum = 0;
    for (int i = lo; i < lo + chunk && i < N_NODES; ++i)
        sum += degs[N_NODES + i] + degs[3 * N_NODES + i];
    s[t] = sum;
    __syncthreads();
    for (int off = 1; off < SCAN_T; off <<= 1) {   // inclusive Hillis-Steele
        int v = (t >= off) ? s[t - off] : 0;
        __syncthreads();
        s[t] += v;
        __syncthreads();
    }
    int run = (t == 0) ? 0 : s[t - 1];
    for (int i = lo; i < lo + chunk && i < N_NODES; ++i) {
        row_ptr[i] = run;
        cursor[i] = run;
        run += degs[N_NODES + i] + degs[3 * N_NODES + i];
    }
    if (t == SCAN_T - 1) row_ptr[N_NODES] = s[SCAN_T - 1];  // total = 2*E
}

// place edges into combined dst-grouped list; rec = {src, coef_bits}
__global__ __launch_bounds__(256) void fill_kernel(const int* __restrict__ src, const int* __restrict__ dst,
        const float* __restrict__ inv_out, const float* __restrict__ inv_in,
        float sign, int* __restrict__ cursor, int2* __restrict__ rec) {
    int e = blockIdx.x * 256 + threadIdx.x;
    if (e < E_EDGES) {
        int u = src[e], v = dst[e];
        float c = sign * inv_out[u] * inv_in[v];
        int p = atomicAdd(&cursor[v], 1);
        rec[p] = make_int2(u, __float_as_int(c));
    }
}

// ---------- MLP ----------
__global__ __launch_bounds__(256) void mlp1_kernel(const float* __restrict__ in_feat,
        const float* __restrict__ W1, const float* __restrict__ b1,
        float* __restrict__ x, float* __restrict__ gsum, float* __restrict__ gsumsq) {
    __shared__ float sW1[IN_F * HID];   // 16 KB
    __shared__ float sRow[8][IN_F];     // 4 KB
    __shared__ float sSum[HID], sSumSq[HID];
    int tid = threadIdx.x;
    for (int i = tid; i < IN_F * HID; i += 256) sW1[i] = W1[i];
    int nb = blockIdx.x * 8;
    for (int i = tid; i < 8 * IN_F; i += 256) {
        int r = i >> 7, c = i & 127;
        sRow[r][c] = in_feat[(size_t)(nb + r) * IN_F + c];
    }
    if (tid < HID) { sSum[tid] = 0.f; sSumSq[tid] = 0.f; }
    __syncthreads();
    int k = tid & 31, r = tid >> 5;
    float acc = b1[k];
    #pragma unroll 8
    for (int j = 0; j < IN_F; ++j) acc = fmaf(sRow[r][j], sW1[j * HID + k], acc);
    x[(size_t)(nb + r) * HID + k] = acc;
    atomicAdd(&sSum[k], acc);
    atomicAdd(&sSumSq[k], acc * acc);
    __syncthreads();
    if (tid < HID) {
        atomicAdd(&gsum[tid], sSum[tid]);
        atomicAdd(&gsumsq[tid], sSumSq[tid]);
    }
}

__global__ void bnparam_kernel(const float* __restrict__ gsum, const float* __restrict__ gsumsq,
        const float* __restrict__ gamma, const float* __restrict__ beta, float* __restrict__ params) {
    int k = threadIdx.x;
    if (k < HID) {
        float mu  = gsum[k]  * (1.0f / (float)N_NODES);
        float var = gsumsq[k] * (1.0f / (float)N_NODES) - mu * mu;
        float s = gamma[k] * rsqrtf(var + 1e-5f);
        params[k]       = s;
        params[HID + k] = beta[k] - mu * s;
    }
}

__global__ __launch_bounds__(256) void mlp2_kernel(const float* __restrict__ x,
        const float* __restrict__ params, const float* __restrict__ W2,
        const float* __restrict__ b2, float* __restrict__ ori_h) {
    __shared__ float sW2[HID * HID];
    __shared__ float sXn[8][HID];
    int tid = threadIdx.x;
    for (int i = tid; i < HID * HID; i += 256) sW2[i] = W2[i];
    int nb = blockIdx.x * 8;
    int k = tid & 31, r = tid >> 5;
    float v = x[(size_t)(nb + r) * HID + k];
    v = fmaxf(fmaf(v, params[k], params[HID + k]), 0.f);
    sXn[r][k] = v;
    __syncthreads();
    float acc = b2[k];
    #pragma unroll
    for (int j = 0; j < HID; ++j) acc = fmaf(sXn[r][j], sW2[j * HID + k], acc);
    ori_h[(size_t)(nb + r) * HID + k] = acc;
}

// ---------- propagation: one half-wave per node, gather-reduce ----------
__global__ __launch_bounds__(256) void gather_kernel(const int* __restrict__ row_ptr,
        const int2* __restrict__ rec, const float* __restrict__ h,
        const float* __restrict__ ori, float* __restrict__ hn) {
    int tid = threadIdx.x;
    int node = blockIdx.x * 8 + (tid >> 5);     // 8 nodes per 256-thread block
    int f = tid & 31;
    int beg = row_ptr[node], end = row_ptr[node + 1];
    float acc = 0.f;
    #pragma unroll 4
    for (int i = beg; i < end; ++i) {
        int2 r = rec[i];                         // broadcast (same addr across half-wave)
        acc = fmaf(__int_as_float(r.y), h[(size_t)r.x * HID + f], acc);
    }
    hn[(size_t)node * HID + f] = ori[(size_t)node * HID + f] + acc;
}

extern "C" void kernel_launch(void* const* d_in, const int* in_sizes, int n_in,
                              void* d_out, int out_size, void* d_ws, size_t ws_size,
                              hipStream_t stream) {
    const float* in_feat = (const float*)d_in[0];
    const float* W1    = (const float*)d_in[1];
    const float* b1    = (const float*)d_in[2];
    const float* gamma = (const float*)d_in[3];
    const float* beta  = (const float*)d_in[4];
    const float* W2    = (const float*)d_in[5];
    const float* b2    = (const float*)d_in[6];
    const int* src  = (const int*)d_in[7];
    const int* dst  = (const int*)d_in[8];
    const int* nsrc = (const int*)d_in[9];
    const int* ndst = (const int*)d_in[10];
    float* out = (float*)d_out;

    // ---- workspace layout ----
    float* ws     = (float*)d_ws;
    float* x      = ws;                                   // N*32 (ping buffer after mlp2)
    float* ori_h  = x + (size_t)N_NODES * HID;            // N*32
    float* invs   = ori_h + (size_t)N_NODES * HID;        // 4*N [out_p, in_p, out_n, in_n]
    float* gsum   = invs + 4 * (size_t)N_NODES;           // 32
    float* gsumsq = gsum + HID;                           // 32
    float* params = gsumsq + HID;                         // 64
    int*   degs   = (int*)(params + 2 * HID);             // 4*N
    int*   row_ptr= degs + 4 * N_NODES;                   // N+1
    int*   cursor = row_ptr + N_NODES + 2;                // N
    uintptr_t rp  = (uintptr_t)(cursor + N_NODES);
    rp = (rp + 15) & ~(uintptr_t)15;
    int2*  rec    = (int2*)rp;                            // 2*E records (51.2 MB)

    hipMemsetAsync(degs, 0, 4 * (size_t)N_NODES * sizeof(int), stream);
    hipMemsetAsync(gsum, 0, 2 * HID * sizeof(float), stream);

    const int EB = E_EDGES / 256;          // 12500, exact
    deg4_kernel<<<EB, 256, 0, stream>>>(src, dst, nsrc, ndst, degs);
    inv_sqrt_kernel<<<(4 * N_NODES + 255) / 256, 256, 0, stream>>>(degs, invs, 4 * N_NODES);
    scan_kernel<<<1, SCAN_T, 0, stream>>>(degs, row_ptr, cursor);
    fill_kernel<<<EB, 256, 0, stream>>>(src,  dst,  invs,               invs + N_NODES,      1.f, cursor, rec);
    fill_kernel<<<EB, 256, 0, stream>>>(nsrc, ndst, invs + 2 * N_NODES, invs + 3 * N_NODES, -1.f, cursor, rec);

    mlp1_kernel<<<N_NODES / 8, 256, 0, stream>>>(in_feat, W1, b1, x, gsum, gsumsq);
    bnparam_kernel<<<1, 64, 0, stream>>>(gsum, gsumsq, gamma, beta, params);
    mlp2_kernel<<<N_NODES / 8, 256, 0, stream>>>(x, params, W2, b2, ori_h);

    // ---- 8 propagation passes; ping-pong x <-> out, ori_h preserved ----
    const float* h = ori_h;
    for (int it = 0; it < PROP; ++it) {
        float* hn = (it & 1) ? out : x;      // it7 (odd) lands in out
        gather_kernel<<<N_NODES / 8, 256, 0, stream>>>(row_ptr, rec, h, ori_h, hn);
        h = hn;
    }
}

// Round 3
// 2058.386 us; speedup vs baseline: 3.0855x; 1.2043x over previous
//
#include <hip/hip_runtime.h>

#define N_NODES 100000
#define E_EDGES 3200000
#define IN_F 128
#define HID 32
#define PROP 8

#define WIN 16384          // nodes per histogram window (64 KB LDS)
#define NWIN 7             // 7*16384 = 114688 >= N
#define HS 16              // edge slices for histogram

// ---------- windowed degree histogram: LDS-aggregated, coalesced flush ----------
__global__ __launch_bounds__(256) void hist_kernel(const int* __restrict__ s, const int* __restrict__ d,
        const int* __restrict__ ns, const int* __restrict__ nd, int* __restrict__ degs) {
    __shared__ int lh[WIN];
    int b = blockIdx.x;
    int w = b % NWIN;
    int st = (b / NWIN) % 4;
    int sl = b / (NWIN * 4);
    const int* p = (st == 0) ? s : (st == 1) ? d : (st == 2) ? ns : nd;
    for (int i = threadIdx.x; i < WIN; i += 256) lh[i] = 0;
    __syncthreads();
    const int lo = w * WIN;
    const int per = E_EDGES / HS;                 // 200000, int4-divisible
    const int4* p4 = (const int4*)(p + sl * per);
    for (int i = threadIdx.x; i < per / 4; i += 256) {
        int4 v = p4[i];
        int a;
        a = v.x - lo; if ((unsigned)a < WIN) atomicAdd(&lh[a], 1);
        a = v.y - lo; if ((unsigned)a < WIN) atomicAdd(&lh[a], 1);
        a = v.z - lo; if ((unsigned)a < WIN) atomicAdd(&lh[a], 1);
        a = v.w - lo; if ((unsigned)a < WIN) atomicAdd(&lh[a], 1);
    }
    __syncthreads();
    int* g = degs + st * N_NODES;
    for (int i = threadIdx.x; i < WIN; i += 256) {
        int idx = lo + i;
        if (idx < N_NODES && lh[i]) atomicAdd(&g[idx], lh[i]);  // coalesced
    }
}

__global__ void inv_sqrt_kernel(const int* __restrict__ deg, float* __restrict__ inv, int n) {
    int i = blockIdx.x * blockDim.x + threadIdx.x;
    if (i < n) inv[i] = rsqrtf(fmaxf((float)deg[i], 1.0f));
}

// ---------- CSR row_ptr: single-block scan of combined in-degree ----------
#define SCAN_T 1024
__global__ __launch_bounds__(SCAN_T) void scan_kernel(const int* __restrict__ degs,
        int* __restrict__ row_ptr, int* __restrict__ cursor) {
    __shared__ int s[SCAN_T];
    int t = threadIdx.x;
    const int chunk = 98;                       // 1024*98 >= N
    int lo = t * chunk;
    int sum = 0;
    for (int i = lo; i < lo + chunk && i < N_NODES; ++i)
        sum += degs[N_NODES + i] + degs[3 * N_NODES + i];
    s[t] = sum;
    __syncthreads();
    for (int off = 1; off < SCAN_T; off <<= 1) {
        int v = (t >= off) ? s[t - off] : 0;
        __syncthreads();
        s[t] += v;
        __syncthreads();
    }
    int run = (t == 0) ? 0 : s[t - 1];
    for (int i = lo; i < lo + chunk && i < N_NODES; ++i) {
        row_ptr[i] = run;
        cursor[i] = run;
        run += degs[N_NODES + i] + degs[3 * N_NODES + i];
    }
    if (t == SCAN_T - 1) row_ptr[N_NODES] = s[SCAN_T - 1];
}

// ---------- placement: both graphs in one dispatch ----------
__global__ __launch_bounds__(256) void fill2_kernel(const int* __restrict__ src, const int* __restrict__ dst,
        const int* __restrict__ nsrc, const int* __restrict__ ndst,
        const float* __restrict__ invs, int* __restrict__ cursor, int2* __restrict__ rec) {
    int e = blockIdx.x * 256 + threadIdx.x;
    int u, v; float sign; const float* io; const float* ii;
    if (e < E_EDGES) {
        u = src[e]; v = dst[e]; sign = 1.f;
        io = invs; ii = invs + N_NODES;
    } else {
        int e2 = e - E_EDGES;
        u = nsrc[e2]; v = ndst[e2]; sign = -1.f;
        io = invs + 2 * N_NODES; ii = invs + 3 * N_NODES;
    }
    float c = sign * io[u] * ii[v];
    int p = atomicAdd(&cursor[v], 1);
    rec[p] = make_int2(u, __float_as_int(c));
}

// ---------- MLP ----------
__global__ __launch_bounds__(256) void mlp1_kernel(const float* __restrict__ in_feat,
        const float* __restrict__ W1, const float* __restrict__ b1,
        float* __restrict__ x, float* __restrict__ gsum, float* __restrict__ gsumsq) {
    __shared__ float sW1[IN_F * HID];
    __shared__ float sRow[8][IN_F];
    __shared__ float sSum[HID], sSumSq[HID];
    int tid = threadIdx.x;
    for (int i = tid; i < IN_F * HID; i += 256) sW1[i] = W1[i];
    int nb = blockIdx.x * 8;
    for (int i = tid; i < 8 * IN_F; i += 256) {
        int r = i >> 7, c = i & 127;
        sRow[r][c] = in_feat[(size_t)(nb + r) * IN_F + c];
    }
    if (tid < HID) { sSum[tid] = 0.f; sSumSq[tid] = 0.f; }
    __syncthreads();
    int k = tid & 31, r = tid >> 5;
    float acc = b1[k];
    #pragma unroll 8
    for (int j = 0; j < IN_F; ++j) acc = fmaf(sRow[r][j], sW1[j * HID + k], acc);
    x[(size_t)(nb + r) * HID + k] = acc;
    atomicAdd(&sSum[k], acc);
    atomicAdd(&sSumSq[k], acc * acc);
    __syncthreads();
    if (tid < HID) {
        atomicAdd(&gsum[tid], sSum[tid]);
        atomicAdd(&gsumsq[tid], sSumSq[tid]);
    }
}

__global__ void bnparam_kernel(const float* __restrict__ gsum, const float* __restrict__ gsumsq,
        const float* __restrict__ gamma, const float* __restrict__ beta, float* __restrict__ params) {
    int k = threadIdx.x;
    if (k < HID) {
        float mu  = gsum[k]  * (1.0f / (float)N_NODES);
        float var = gsumsq[k] * (1.0f / (float)N_NODES) - mu * mu;
        float s = gamma[k] * rsqrtf(var + 1e-5f);
        params[k]       = s;
        params[HID + k] = beta[k] - mu * s;
    }
}

__global__ __launch_bounds__(256) void mlp2_kernel(const float* __restrict__ x,
        const float* __restrict__ params, const float* __restrict__ W2,
        const float* __restrict__ b2, float* __restrict__ ori_h) {
    __shared__ float sW2[HID * HID];
    __shared__ float sXn[8][HID];
    int tid = threadIdx.x;
    for (int i = tid; i < HID * HID; i += 256) sW2[i] = W2[i];
    int nb = blockIdx.x * 8;
    int k = tid & 31, r = tid >> 5;
    float v = x[(size_t)(nb + r) * HID + k];
    v = fmaxf(fmaf(v, params[k], params[HID + k]), 0.f);
    sXn[r][k] = v;
    __syncthreads();
    float acc = b2[k];
    #pragma unroll
    for (int j = 0; j < HID; ++j) acc = fmaf(sXn[r][j], sW2[j * HID + k], acc);
    ori_h[(size_t)(nb + r) * HID + k] = acc;
}

// ---------- propagation: half-wave per node, 4-way ILP gather ----------
__global__ __launch_bounds__(256) void gather_kernel(const int* __restrict__ row_ptr,
        const int2* __restrict__ rec, const float* __restrict__ h,
        const float* __restrict__ ori, float* __restrict__ hn) {
    int tid = threadIdx.x;
    int node = blockIdx.x * 8 + (tid >> 5);
    int f = tid & 31;
    int beg = row_ptr[node], end = row_ptr[node + 1];
    float acc0 = 0.f, acc1 = 0.f, acc2 = 0.f, acc3 = 0.f;
    int i = beg;
    if ((i & 1) && i < end) {                    // align to 16 B
        int2 r = rec[i];
        acc0 = fmaf(__int_as_float(r.y), h[r.x * HID + f], acc0);
        ++i;
    }
    for (; i + 4 <= end; i += 4) {
        int4 a = *(const int4*)(rec + i);
        int4 b = *(const int4*)(rec + i + 2);
        acc0 = fmaf(__int_as_float(a.y), h[a.x * HID + f], acc0);
        acc1 = fmaf(__int_as_float(a.w), h[a.z * HID + f], acc1);
        acc2 = fmaf(__int_as_float(b.y), h[b.x * HID + f], acc2);
        acc3 = fmaf(__int_as_float(b.w), h[b.z * HID + f], acc3);
    }
    for (; i < end; ++i) {
        int2 r = rec[i];
        acc0 = fmaf(__int_as_float(r.y), h[r.x * HID + f], acc0);
    }
    int o = node * HID + f;
    hn[o] = ori[o] + ((acc0 + acc1) + (acc2 + acc3));
}

extern "C" void kernel_launch(void* const* d_in, const int* in_sizes, int n_in,
                              void* d_out, int out_size, void* d_ws, size_t ws_size,
                              hipStream_t stream) {
    const float* in_feat = (const float*)d_in[0];
    const float* W1    = (const float*)d_in[1];
    const float* b1    = (const float*)d_in[2];
    const float* gamma = (const float*)d_in[3];
    const float* beta  = (const float*)d_in[4];
    const float* W2    = (const float*)d_in[5];
    const float* b2    = (const float*)d_in[6];
    const int* src  = (const int*)d_in[7];
    const int* dst  = (const int*)d_in[8];
    const int* nsrc = (const int*)d_in[9];
    const int* ndst = (const int*)d_in[10];
    float* out = (float*)d_out;

    // ---- workspace layout ----
    float* ws     = (float*)d_ws;
    float* x      = ws;                                   // N*32
    float* ori_h  = x + (size_t)N_NODES * HID;            // N*32
    float* invs   = ori_h + (size_t)N_NODES * HID;        // 4*N
    float* gsum   = invs + 4 * (size_t)N_NODES;           // 32
    float* gsumsq = gsum + HID;                           // 32
    float* params = gsumsq + HID;                         // 64
    int*   degs   = (int*)(params + 2 * HID);             // 4*N
    int*   row_ptr= degs + 4 * N_NODES;                   // N+1
    int*   cursor = row_ptr + N_NODES + 2;                // N
    uintptr_t rp  = (uintptr_t)(cursor + N_NODES);
    rp = (rp + 15) & ~(uintptr_t)15;
    int2*  rec    = (int2*)rp;                            // 2*E records (51.2 MB)

    hipMemsetAsync(degs, 0, 4 * (size_t)N_NODES * sizeof(int), stream);
    hipMemsetAsync(gsum, 0, 2 * HID * sizeof(float), stream);

    hist_kernel<<<NWIN * 4 * HS, 256, 0, stream>>>(src, dst, nsrc, ndst, degs);
    inv_sqrt_kernel<<<(4 * N_NODES + 255) / 256, 256, 0, stream>>>(degs, invs, 4 * N_NODES);
    scan_kernel<<<1, SCAN_T, 0, stream>>>(degs, row_ptr, cursor);
    fill2_kernel<<<2 * E_EDGES / 256, 256, 0, stream>>>(src, dst, nsrc, ndst, invs, cursor, rec);

    mlp1_kernel<<<N_NODES / 8, 256, 0, stream>>>(in_feat, W1, b1, x, gsum, gsumsq);
    bnparam_kernel<<<1, 64, 0, stream>>>(gsum, gsumsq, gamma, beta, params);
    mlp2_kernel<<<N_NODES / 8, 256, 0, stream>>>(x, params, W2, b2, ori_h);

    const float* h = ori_h;
    for (int it = 0; it < PROP; ++it) {
        float* hn = (it & 1) ? out : x;      // last (it=7, odd) lands in out
        gather_kernel<<<N_NODES / 8, 256, 0, stream>>>(row_ptr, rec, h, ori_h, hn);
        h = hn;
    }
}

// Round 4
// 1649.146 us; speedup vs baseline: 3.8512x; 1.2482x over previous
//
#include <hip/hip_runtime.h>

#define N_NODES 100000
#define E_EDGES 3200000
#define IN_F 128
#define HID 32
#define PROP 8

#define WIN 16384          // nodes per histogram window (64 KB LDS)
#define NWIN 7             // 7*16384 = 114688 >= N
#define HS 16              // edge slices for histogram

#define MB_ROWS 64
#define MB_BLOCKS ((N_NODES + MB_ROWS - 1) / MB_ROWS)   // 1563
#define SCB 98             // scan blocks: 98*1024 >= N

// ---------- windowed degree histogram: LDS-aggregated, coalesced flush ----------
__global__ __launch_bounds__(256) void hist_kernel(const int* __restrict__ s, const int* __restrict__ d,
        const int* __restrict__ ns, const int* __restrict__ nd, int* __restrict__ degs) {
    __shared__ int lh[WIN];
    int b = blockIdx.x;
    int w = b % NWIN;
    int st = (b / NWIN) % 4;
    int sl = b / (NWIN * 4);
    const int* p = (st == 0) ? s : (st == 1) ? d : (st == 2) ? ns : nd;
    for (int i = threadIdx.x; i < WIN; i += 256) lh[i] = 0;
    __syncthreads();
    const int lo = w * WIN;
    const int per = E_EDGES / HS;
    const int4* p4 = (const int4*)(p + sl * per);
    for (int i = threadIdx.x; i < per / 4; i += 256) {
        int4 v = p4[i];
        int a;
        a = v.x - lo; if ((unsigned)a < WIN) atomicAdd(&lh[a], 1);
        a = v.y - lo; if ((unsigned)a < WIN) atomicAdd(&lh[a], 1);
        a = v.z - lo; if ((unsigned)a < WIN) atomicAdd(&lh[a], 1);
        a = v.w - lo; if ((unsigned)a < WIN) atomicAdd(&lh[a], 1);
    }
    __syncthreads();
    int* g = degs + st * N_NODES;
    for (int i = threadIdx.x; i < WIN; i += 256) {
        int idx = lo + i;
        if (idx < N_NODES && lh[i]) atomicAdd(&g[idx], lh[i]);
    }
}

__global__ void inv_sqrt_kernel(const int* __restrict__ deg, float* __restrict__ inv, int n) {
    int i = blockIdx.x * blockDim.x + threadIdx.x;
    if (i < n) inv[i] = rsqrtf(fmaxf((float)deg[i], 1.0f));
}

// ---------- 3-stage parallel scan of combined in-degree ----------
__global__ __launch_bounds__(1024) void scanA_kernel(const int* __restrict__ degs,
        int* __restrict__ row_ptr, int* __restrict__ blockSums) {
    __shared__ int sh[1024];
    int t = threadIdx.x, b = blockIdx.x;
    int i = b * 1024 + t;
    int v = (i < N_NODES) ? (degs[N_NODES + i] + degs[3 * N_NODES + i]) : 0;
    sh[t] = v;
    __syncthreads();
    for (int off = 1; off < 1024; off <<= 1) {
        int u = (t >= off) ? sh[t - off] : 0;
        __syncthreads();
        sh[t] += u;
        __syncthreads();
    }
    if (i < N_NODES) row_ptr[i] = sh[t] - v;    // exclusive, pre-offset
    if (t == 1023) blockSums[b] = sh[1023];
}

__global__ __launch_bounds__(128) void scanB_kernel(const int* __restrict__ blockSums,
        int* __restrict__ blockOff) {
    __shared__ int sh[128];
    int t = threadIdx.x;
    int v = (t < SCB) ? blockSums[t] : 0;
    sh[t] = v;
    __syncthreads();
    for (int off = 1; off < 128; off <<= 1) {
        int u = (t >= off) ? sh[t - off] : 0;
        __syncthreads();
        sh[t] += u;
        __syncthreads();
    }
    if (t < SCB) blockOff[t] = sh[t] - v;       // exclusive block offsets
}

__global__ __launch_bounds__(1024) void scanC_kernel(int* __restrict__ row_ptr,
        const int* __restrict__ blockOff, int* __restrict__ cursor) {
    int b = blockIdx.x, t = threadIdx.x;
    int i = b * 1024 + t;
    if (i < N_NODES) {
        int v = row_ptr[i] + blockOff[b];
        row_ptr[i] = v;
        cursor[i] = v;
    }
    if (i == 0) row_ptr[N_NODES] = 2 * E_EDGES;
}

// ---------- placement: both graphs in one dispatch ----------
__global__ __launch_bounds__(256) void fill2_kernel(const int* __restrict__ src, const int* __restrict__ dst,
        const int* __restrict__ nsrc, const int* __restrict__ ndst,
        const float* __restrict__ invs, int* __restrict__ cursor, int2* __restrict__ rec) {
    int e = blockIdx.x * 256 + threadIdx.x;
    int u, v; float sign; const float* io; const float* ii;
    if (e < E_EDGES) {
        u = src[e]; v = dst[e]; sign = 1.f;
        io = invs; ii = invs + N_NODES;
    } else {
        int e2 = e - E_EDGES;
        u = nsrc[e2]; v = ndst[e2]; sign = -1.f;
        io = invs + 2 * N_NODES; ii = invs + 3 * N_NODES;
    }
    float c = sign * io[u] * ii[v];
    int p = atomicAdd(&cursor[v], 1);
    rec[p] = make_int2(u, __float_as_int(c));
}

// ---------- MLP stage 1: x = in_feat@W1 + b1, per-block batch-stat partials ----------
// 64 rows/block; thread tile = 2 rows x 4 cols; in_feat staged as xor-swizzled
// float4 quads (conflict-free b128); W1 transposed+padded (broadcast b128).
__global__ __launch_bounds__(256) void mlp1_kernel(const float* __restrict__ in_feat,
        const float* __restrict__ W1, const float* __restrict__ b1,
        float* __restrict__ x, float* __restrict__ partials) {
    __shared__ float4 sRow4[MB_ROWS * 32];      // 32 KB
    __shared__ float  sW1t[32 * 132];           // 16.9 KB
    int tid = threadIdx.x;
    for (int idx = tid; idx < IN_F * HID; idx += 256) {
        int j = idx >> 5, k = idx & 31;
        sW1t[k * 132 + j] = W1[idx];            // transpose: sW1t[k][j]
    }
    int nb = blockIdx.x * MB_ROWS;
    const float4* inf4 = (const float4*)in_feat;
    for (int idx = tid; idx < MB_ROWS * 32; idx += 256) {
        int row = idx >> 5, q = idx & 31;
        int g = nb + row;
        float4 v = (g < N_NODES) ? inf4[(size_t)g * 32 + q] : make_float4(0.f, 0.f, 0.f, 0.f);
        sRow4[row * 32 + (q ^ (row & 31))] = v; // swizzled quad
    }
    __syncthreads();
    int rt = tid & 31, kt = tid >> 5;           // rt: row lane, kt: 0..7 col group
    int k0 = kt * 4;
    float acc[2][4] = {{0.f}};
    const float4* w0p = (const float4*)&sW1t[(k0 + 0) * 132];
    const float4* w1p = (const float4*)&sW1t[(k0 + 1) * 132];
    const float4* w2p = (const float4*)&sW1t[(k0 + 2) * 132];
    const float4* w3p = (const float4*)&sW1t[(k0 + 3) * 132];
    #pragma unroll 4
    for (int jq = 0; jq < 32; ++jq) {
        int pq = jq ^ rt;
        float4 a0 = sRow4[rt * 32 + pq];
        float4 a1 = sRow4[(rt + 32) * 32 + pq];
        float4 w0 = w0p[jq], w1 = w1p[jq], w2 = w2p[jq], w3 = w3p[jq];
        acc[0][0] += a0.x*w0.x + a0.y*w0.y + a0.z*w0.z + a0.w*w0.w;
        acc[0][1] += a0.x*w1.x + a0.y*w1.y + a0.z*w1.z + a0.w*w1.w;
        acc[0][2] += a0.x*w2.x + a0.y*w2.y + a0.z*w2.z + a0.w*w2.w;
        acc[0][3] += a0.x*w3.x + a0.y*w3.y + a0.z*w3.z + a0.w*w3.w;
        acc[1][0] += a1.x*w0.x + a1.y*w0.y + a1.z*w0.z + a1.w*w0.w;
        acc[1][1] += a1.x*w1.x + a1.y*w1.y + a1.z*w1.z + a1.w*w1.w;
        acc[1][2] += a1.x*w2.x + a1.y*w2.y + a1.z*w2.z + a1.w*w2.w;
        acc[1][3] += a1.x*w3.x + a1.y*w3.y + a1.z*w3.z + a1.w*w3.w;
    }
    float bb[4] = { b1[k0], b1[k0 + 1], b1[k0 + 2], b1[k0 + 3] };
    float s[4] = {0.f, 0.f, 0.f, 0.f}, ss[4] = {0.f, 0.f, 0.f, 0.f};
    #pragma unroll
    for (int i = 0; i < 2; ++i) {
        int row = nb + rt + 32 * i;
        if (row < N_NODES) {
            float4 o;
            o.x = acc[i][0] + bb[0];
            o.y = acc[i][1] + bb[1];
            o.z = acc[i][2] + bb[2];
            o.w = acc[i][3] + bb[3];
            *(float4*)&x[(size_t)row * HID + k0] = o;
            s[0] += o.x; ss[0] += o.x * o.x;
            s[1] += o.y; ss[1] += o.y * o.y;
            s[2] += o.z; ss[2] += o.z * o.z;
            s[3] += o.w; ss[3] += o.w * o.w;
        }
    }
    for (int off = 16; off; off >>= 1) {
        #pragma unroll
        for (int c = 0; c < 4; ++c) {
            s[c]  += __shfl_down(s[c],  off, 32);
            ss[c] += __shfl_down(ss[c], off, 32);
        }
    }
    if (rt == 0) {
        float* pb = partials + (size_t)blockIdx.x * 64;
        #pragma unroll
        for (int c = 0; c < 4; ++c) {
            pb[k0 + c]      = s[c];
            pb[32 + k0 + c] = ss[c];
        }
    }
}

// ---------- reduce partials -> BN scale/shift ----------
__global__ __launch_bounds__(256) void bnparam_kernel(const float* __restrict__ partials,
        const float* __restrict__ gamma, const float* __restrict__ beta, float* __restrict__ params) {
    __shared__ float red[4][64];
    int t = threadIdx.x;
    int col = t & 63, ch = t >> 6;
    float sum = 0.f;
    for (int g = ch; g < MB_BLOCKS; g += 4) sum += partials[(size_t)g * 64 + col];
    red[ch][col] = sum;
    __syncthreads();
    if (t < 64) red[0][t] = red[0][t] + red[1][t] + red[2][t] + red[3][t];
    __syncthreads();
    if (t < HID) {
        float mu  = red[0][t] * (1.0f / (float)N_NODES);
        float var = red[0][t + 32] * (1.0f / (float)N_NODES) - mu * mu;
        float sg = gamma[t] * rsqrtf(var + 1e-5f);
        params[t]       = sg;
        params[HID + t] = beta[t] - mu * sg;
    }
}

// ---------- MLP stage 2: ori_h = relu(bn(x)) @ W2 + b2 ----------
__global__ __launch_bounds__(256) void mlp2_kernel(const float* __restrict__ x,
        const float* __restrict__ params, const float* __restrict__ W2,
        const float* __restrict__ b2, float* __restrict__ ori_h) {
    __shared__ float sW2[HID * HID];
    __shared__ float sXn[8][HID];
    int tid = threadIdx.x;
    for (int i = tid; i < HID * HID; i += 256) sW2[i] = W2[i];
    int nb = blockIdx.x * 8;
    int k = tid & 31, r = tid >> 5;
    float v = x[(size_t)(nb + r) * HID + k];
    v = fmaxf(fmaf(v, params[k], params[HID + k]), 0.f);
    sXn[r][k] = v;
    __syncthreads();
    float acc = b2[k];
    #pragma unroll
    for (int j = 0; j < HID; ++j) acc = fmaf(sXn[r][j], sW2[j * HID + k], acc);
    ori_h[(size_t)(nb + r) * HID + k] = acc;
}

// ---------- propagation: half-wave per node, 4-way ILP gather ----------
__global__ __launch_bounds__(256) void gather_kernel(const int* __restrict__ row_ptr,
        const int2* __restrict__ rec, const float* __restrict__ h,
        const float* __restrict__ ori, float* __restrict__ hn) {
    int tid = threadIdx.x;
    int node = blockIdx.x * 8 + (tid >> 5);
    int f = tid & 31;
    int beg = row_ptr[node], end = row_ptr[node + 1];
    float acc0 = 0.f, acc1 = 0.f, acc2 = 0.f, acc3 = 0.f;
    int i = beg;
    if ((i & 1) && i < end) {
        int2 r = rec[i];
        acc0 = fmaf(__int_as_float(r.y), h[r.x * HID + f], acc0);
        ++i;
    }
    for (; i + 4 <= end; i += 4) {
        int4 a = *(const int4*)(rec + i);
        int4 b = *(const int4*)(rec + i + 2);
        acc0 = fmaf(__int_as_float(a.y), h[a.x * HID + f], acc0);
        acc1 = fmaf(__int_as_float(a.w), h[a.z * HID + f], acc1);
        acc2 = fmaf(__int_as_float(b.y), h[b.x * HID + f], acc2);
        acc3 = fmaf(__int_as_float(b.w), h[b.z * HID + f], acc3);
    }
    for (; i < end; ++i) {
        int2 r = rec[i];
        acc0 = fmaf(__int_as_float(r.y), h[r.x * HID + f], acc0);
    }
    int o = node * HID + f;
    hn[o] = ori[o] + ((acc0 + acc1) + (acc2 + acc3));
}

extern "C" void kernel_launch(void* const* d_in, const int* in_sizes, int n_in,
                              void* d_out, int out_size, void* d_ws, size_t ws_size,
                              hipStream_t stream) {
    const float* in_feat = (const float*)d_in[0];
    const float* W1    = (const float*)d_in[1];
    const float* b1    = (const float*)d_in[2];
    const float* gamma = (const float*)d_in[3];
    const float* beta  = (const float*)d_in[4];
    const float* W2    = (const float*)d_in[5];
    const float* b2    = (const float*)d_in[6];
    const int* src  = (const int*)d_in[7];
    const int* dst  = (const int*)d_in[8];
    const int* nsrc = (const int*)d_in[9];
    const int* ndst = (const int*)d_in[10];
    float* out = (float*)d_out;

    // ---- workspace layout ----
    float* ws      = (float*)d_ws;
    float* x       = ws;                                   // N*32
    float* ori_h   = x + (size_t)N_NODES * HID;            // N*32
    float* invs    = ori_h + (size_t)N_NODES * HID;        // 4*N
    float* params  = invs + 4 * (size_t)N_NODES;           // 64
    float* partials= params + 2 * HID;                     // MB_BLOCKS*64
    int*   degs    = (int*)(partials + (size_t)MB_BLOCKS * 64);  // 4*N
    int*   row_ptr = degs + 4 * N_NODES;                   // N+1
    int*   cursor  = row_ptr + N_NODES + 2;                // N
    int*   blockSums = cursor + N_NODES;                   // SCB
    int*   blockOff  = blockSums + 128;                    // SCB
    uintptr_t rp  = (uintptr_t)(blockOff + 128);
    rp = (rp + 15) & ~(uintptr_t)15;
    int2*  rec    = (int2*)rp;                             // 2*E records (51.2 MB)

    hipMemsetAsync(degs, 0, 4 * (size_t)N_NODES * sizeof(int), stream);

    hist_kernel<<<NWIN * 4 * HS, 256, 0, stream>>>(src, dst, nsrc, ndst, degs);
    inv_sqrt_kernel<<<(4 * N_NODES + 255) / 256, 256, 0, stream>>>(degs, invs, 4 * N_NODES);
    scanA_kernel<<<SCB, 1024, 0, stream>>>(degs, row_ptr, blockSums);
    scanB_kernel<<<1, 128, 0, stream>>>(blockSums, blockOff);
    scanC_kernel<<<SCB, 1024, 0, stream>>>(row_ptr, blockOff, cursor);
    fill2_kernel<<<2 * E_EDGES / 256, 256, 0, stream>>>(src, dst, nsrc, ndst, invs, cursor, rec);

    mlp1_kernel<<<MB_BLOCKS, 256, 0, stream>>>(in_feat, W1, b1, x, partials);
    bnparam_kernel<<<1, 256, 0, stream>>>(partials, gamma, beta, params);
    mlp2_kernel<<<N_NODES / 8, 256, 0, stream>>>(x, params, W2, b2, ori_h);

    const float* h = ori_h;
    for (int it = 0; it < PROP; ++it) {
        float* hn = (it & 1) ? out : x;      // last (it=7, odd) lands in out
        gather_kernel<<<N_NODES / 8, 256, 0, stream>>>(row_ptr, rec, h, ori_h, hn);
        h = hn;
    }
}